// Round 9
// baseline (471.464 us; speedup 1.0000x reference)
//
#include <hip/hip_runtime.h>
#include <hip/hip_bf16.h>
#include <stdint.h>

typedef __attribute__((ext_vector_type(8)))  short    short8;
typedef __attribute__((ext_vector_type(4)))  float    floatx4;
typedef __attribute__((ext_vector_type(16))) float    floatx16;
typedef __attribute__((ext_vector_type(2)))  uint32_t uintx2;

// HW packed fp32->bf16 (RTNE), low half = first operand.
static __device__ __forceinline__ uint32_t cvtpk(float lo, float hi) {
  uint32_t r;
  asm("v_cvt_pk_bf16_f32 %0, %1, %2" : "=v"(r) : "v"(lo), "v"(hi));
  return r;
}

static __device__ __forceinline__ short8 pack8c(floatx4 a, floatx4 b) {
  union { uint32_t u[4]; short8 s; } r;
  r.u[0] = cvtpk(a[0], a[1]); r.u[1] = cvtpk(a[2], a[3]);
  r.u[2] = cvtpk(b[0], b[1]); r.u[3] = cvtpk(b[2], b[3]);
  return r.s;
}

#define MFMA32(a, b, c) __builtin_amdgcn_mfma_f32_32x32x16_bf16((a), (b), (c), 0, 0, 0)

// end-of-tile barrier: retire LDS ops, then s_barrier. Global loads stay in flight (T4).
#define TILE_BARRIER() asm volatile("s_waitcnt lgkmcnt(0)\n\ts_barrier" ::: "memory")

constexpr int S_LEN = 2048;
constexpr int DH    = 64;
constexpr int QBLK  = 128;   // 4 waves x 32 q-rows
constexpr int KVBLK = 64;
constexpr int NT    = S_LEN / KVBLK;          // 32
constexpr size_t NROWS = 32 * (size_t)S_LEN;  // bh * q rows = 65536

// permlane32_swap: new_a = [a.lo32, b.lo32] ; new_b = [a.hi32, b.hi32]
static __device__ __forceinline__ void swap32(uint32_t& a, uint32_t& b, int hi) {
#if __has_builtin(__builtin_amdgcn_permlane32_swap)
  typedef int intx2 __attribute__((ext_vector_type(2)));
  intx2 r = __builtin_amdgcn_permlane32_swap((int)a, (int)b, false, false);
  a = (uint32_t)r[0]; b = (uint32_t)r[1];
#else
  uint32_t pa = (uint32_t)__shfl_xor((int)a, 32, 64);
  uint32_t pb = (uint32_t)__shfl_xor((int)b, 32, 64);
  uint32_t na = hi ? pb : a;
  uint32_t nb = hi ? b  : pa;
  a = na; b = nb;
#endif
}

// (256,3): unified VGPR+AGPR budget 170/wave -> 3 waves/SIMD. r8's (256,2) left
// ~184 live regs -> 2 waves/SIMD cap (the actual occupancy limiter; grid wasn't).
template<bool SPLIT>
__global__ __launch_bounds__(256, 3)
void attn_fwd(const float* __restrict__ Q, const float* __restrict__ V,
              const float* __restrict__ K, const float* __restrict__ AM,
              const float* __restrict__ SM, float* __restrict__ O,
              float* __restrict__ PO1, float* __restrict__ PM, float* __restrict__ PL)
{
  __shared__ ushort Kl[2][KVBLK * DH];   // [kv][d]  bf16, chunk^=(row&7) swizzle
  __shared__ ushort Vt[2][DH * KVBLK];   // [d][kv]  bf16 (plain V), swizzled

  const int bh   = blockIdx.x;
  const int qt   = blockIdx.y;
  const int kvh  = SPLIT ? blockIdx.z : 0;
  const int NT_LOC = SPLIT ? NT / 2 : NT;
  const int t0   = kvh * NT_LOC;
  const int tlast = t0 + NT_LOC - 1;

  const int tid  = threadIdx.x;
  const int lane = tid & 63;
  const int wave = tid >> 6;
  const int l31  = lane & 31;
  const int hi   = lane >> 5;

  const float* qptr  = Q  + (size_t)bh * S_LEN * DH;
  const float* kptr  = K  + (size_t)bh * S_LEN * DH;
  const float* vptr  = V  + (size_t)bh * S_LEN * DH;
  const float* amptr = AM + (size_t)(bh >> 4) * S_LEN * S_LEN;
  const float* smptr = SM + (size_t)(bh >> 4) * S_LEN;

  const int qw = qt * QBLK + wave * 32;  // this wave's q base

  // ---- Q fragments: lane holds Q[qw + (l&31)][s*16 + hi*8 + 0..7] ----
  short8 qf[4];
  {
    const float* p = qptr + (size_t)(qw + l31) * DH + hi * 8;
    #pragma unroll
    for (int s = 0; s < 4; ++s) {
      floatx4 f0 = *(const floatx4*)(p + s * 16);
      floatx4 f1 = *(const floatx4*)(p + s * 16 + 4);
      qf[s] = pack8c(f0, f1);
    }
  }

  // staging indices
  const int krow = tid >> 2;          // K: one kv row, 16 d
  const int kcol = (tid & 3) * 16;
  const int kcb  = (tid & 3) * 2;
  const int vr0  = (tid & 15) * 4;    // V: 4 kv rows, 4 d
  const int vd0  = (tid >> 4) * 4;

  floatx4 kreg[4], vreg[4];
  floatx4 amx[2][4];                  // SINGLE am buffer (reloaded in place)

  auto LOADKV = [&](int t) {
    const float* kg = kptr + (size_t)(t * KVBLK + krow) * DH + kcol;
    #pragma unroll
    for (int j = 0; j < 4; ++j) kreg[j] = ((const floatx4*)kg)[j];
    #pragma unroll
    for (int i = 0; i < 4; ++i)
      vreg[i] = *(const floatx4*)(vptr + (size_t)(t * KVBLK + vr0 + i) * DH + vd0);
  };

  auto WRITEKV = [&](int c) {
    // K tile [kv][d]
    const int sw = krow & 7;
    *(short8*)&Kl[c][krow * 64 + ((kcb ^ sw) * 8)]       = pack8c(kreg[0], kreg[1]);
    *(short8*)&Kl[c][krow * 64 + (((kcb + 1) ^ sw) * 8)] = pack8c(kreg[2], kreg[3]);
    // V^T tile [d][kv] (plain bf16(V))
    #pragma unroll
    for (int d = 0; d < 4; ++d) {
      uintx2 w;
      w[0] = cvtpk(vreg[0][d], vreg[1][d]);
      w[1] = cvtpk(vreg[2][d], vreg[3][d]);
      const int row = vd0 + d;
      const int ch  = (vr0 >> 3) ^ (row & 7);
      *(uintx2*)&Vt[c][row * 64 + ch * 8 + (vr0 & 7)] = w;
    }
  };

  auto LOADAM = [&](int t) {
    const float* base = amptr + (size_t)(qw + l31) * S_LEN + t * KVBLK + hi * 4;
    #pragma unroll
    for (int blk = 0; blk < 2; ++blk)
      #pragma unroll
      for (int j = 0; j < 4; ++j)
        amx[blk][j] = *(const floatx4*)(base + blk * 32 + j * 8);
  };

  // prologue: stage first tile, one full barrier
  LOADKV(t0);
  WRITEKV(0);
  LOADAM(t0);
  TILE_BARRIER();

  float m_run = -3.0e38f, l_run = 0.f;
  floatx16 oacc[2];
  #pragma unroll
  for (int db = 0; db < 2; ++db)
    #pragma unroll
    for (int r = 0; r < 16; ++r) oacc[db][r] = 0.f;

  // one K/V-tile step; tt = global tile; c = LDS buffer of tile tt
  auto STEP = [&](int tt, int c) {
    // ---- QK^T: sc[blk] = S^T[kv][q]; lane q=l31, kv = blk*32+crow(r,hi) ----
    floatx16 sc[2];   // MFMA acc -> scores -> P, all IN PLACE (register reuse)
    __builtin_amdgcn_s_setprio(1);
    #pragma unroll
    for (int blk = 0; blk < 2; ++blk) {
      #pragma unroll
      for (int r = 0; r < 16; ++r) sc[blk][r] = 0.f;
      const int row = blk * 32 + l31;
      const int sw  = row & 7;
      #pragma unroll
      for (int s = 0; s < 4; ++s) {
        const int ch = (s * 2 + hi) ^ sw;
        short8 kf = *(const short8*)&Kl[c][row * 64 + ch * 8];
        sc[blk] = MFMA32(kf, qf[s], sc[blk]);
      }
    }
    __builtin_amdgcn_s_setprio(0);

    // ---- issue next K/V loads early (consumed at WRITEKV, tile end) ----
    const int tn = (tt < tlast) ? tt + 1 : tlast;
    LOADKV(tn);

    // ---- scores in place (consumes amx from previous LOADAM) ----
    float pmax = -3.0e38f;
    #pragma unroll
    for (int blk = 0; blk < 2; ++blk)
      #pragma unroll
      for (int r = 0; r < 16; ++r) {
        const float v = fmaf(sc[blk][r], 0.125f, amx[blk][r >> 2][r & 3]);
        sc[blk][r] = v;
        pmax = fmaxf(pmax, v);
      }
    pmax = fmaxf(pmax, __shfl_xor(pmax, 32, 64));

    // ---- am regs now dead: reload same buffer for next tile (no copy) ----
    LOADAM(tn);

    // ---- seq_mask fragments (global, L1/L2 broadcast) ----
    floatx4 smv[2][4];
    #pragma unroll
    for (int blk = 0; blk < 2; ++blk)
      #pragma unroll
      for (int j = 0; j < 4; ++j)
        smv[blk][j] = *(const floatx4*)(smptr + tt * KVBLK + blk * 32 + hi * 4 + j * 8);

    // ---- online rescale (skip is bit-exact when no row grew: fac==1.0) ----
    if (__any(pmax > m_run)) {
      const float mnew = fmaxf(m_run, pmax);
      const float fac  = __expf(m_run - mnew);
      float fw[16];
      #pragma unroll
      for (int r = 0; r < 16; ++r)
        fw[r] = __shfl(fac, (r & 3) + 8 * (r >> 2) + 4 * hi, 64);
      #pragma unroll
      for (int db = 0; db < 2; ++db)
        #pragma unroll
        for (int r = 0; r < 16; ++r) oacc[db][r] *= fw[r];
      l_run *= fac;
      m_run = mnew;
    }

    // ---- P = exp(s - m) in place; denominator from UNROUNDED fp32 P ----
    float ssum = 0.f;
    #pragma unroll
    for (int blk = 0; blk < 2; ++blk)
      #pragma unroll
      for (int r = 0; r < 16; ++r) {
        const float e = __expf(sc[blk][r] - m_run);
        sc[blk][r] = e;
        ssum += e;
      }
    ssum += __shfl_xor(ssum, 32, 64);
    l_run += ssum;

    // ---- (P * sm) -> bf16 A-fragments (cvt_pk + permlane32_swap) ----
    uint32_t pw[2][2][4];
    #pragma unroll
    for (int blk = 0; blk < 2; ++blk)
      #pragma unroll
      for (int ks = 0; ks < 2; ++ks) {
        uint32_t w0 = cvtpk(sc[blk][ks * 8 + 0] * smv[blk][ks * 2 + 0][0],
                            sc[blk][ks * 8 + 1] * smv[blk][ks * 2 + 0][1]);
        uint32_t w1 = cvtpk(sc[blk][ks * 8 + 2] * smv[blk][ks * 2 + 0][2],
                            sc[blk][ks * 8 + 3] * smv[blk][ks * 2 + 0][3]);
        uint32_t w2 = cvtpk(sc[blk][ks * 8 + 4] * smv[blk][ks * 2 + 1][0],
                            sc[blk][ks * 8 + 5] * smv[blk][ks * 2 + 1][1]);
        uint32_t w3 = cvtpk(sc[blk][ks * 8 + 6] * smv[blk][ks * 2 + 1][2],
                            sc[blk][ks * 8 + 7] * smv[blk][ks * 2 + 1][3]);
        swap32(w0, w2, hi);
        swap32(w1, w3, hi);
        pw[blk][ks][0] = w0; pw[blk][ks][1] = w1;
        pw[blk][ks][2] = w2; pw[blk][ks][3] = w3;
      }

    // ---- PV: oacc[db] += (P.sm)(32q x 64kv) . V(64kv x 64d) ----
    __builtin_amdgcn_s_setprio(1);
    #pragma unroll
    for (int blk = 0; blk < 2; ++blk)
      #pragma unroll
      for (int ks = 0; ks < 2; ++ks) {
        union { uint32_t u[4]; short8 s; } af;
        af.u[0] = pw[blk][ks][0]; af.u[1] = pw[blk][ks][1];
        af.u[2] = pw[blk][ks][2]; af.u[3] = pw[blk][ks][3];
        #pragma unroll
        for (int db = 0; db < 2; ++db) {
          const int row = db * 32 + l31;
          const int ch  = (blk * 4 + ks * 2 + hi) ^ (row & 7);
          short8 vf = *(const short8*)&Vt[c][row * 64 + ch * 8];
          oacc[db] = MFMA32(af.s, vf, oacc[db]);
        }
      }
    __builtin_amdgcn_s_setprio(0);

    // ---- write staged tile into the other buffer; single barrier per tile ----
    WRITEKV(c ^ 1);
    TILE_BARRIER();
  };

  #pragma unroll 1
  for (int t = 0; t < NT_LOC; t += 2) {
    STEP(t0 + t,     0);
    STEP(t0 + t + 1, 1);
  }

  // ---- epilogue ----
  if (SPLIT) {
    float* po = (kvh == 0) ? O : PO1;
    po += (size_t)bh * S_LEN * DH;
    #pragma unroll
    for (int db = 0; db < 2; ++db)
      #pragma unroll
      for (int r = 0; r < 16; ++r) {
        const int qr = (r & 3) + 8 * (r >> 2) + 4 * hi;
        po[(size_t)(qw + qr) * DH + db * 32 + l31] = oacc[db][r];
      }
    if (hi == 0) {
      const size_t ri = (size_t)kvh * NROWS + (size_t)bh * S_LEN + qw + l31;
      PM[ri] = m_run;
      PL[ri] = l_run;
    }
  } else {
    float* optr = O + (size_t)bh * S_LEN * DH;
    const float inv = 1.0f / l_run;
    float iw[16];
    #pragma unroll
    for (int r = 0; r < 16; ++r)
      iw[r] = __shfl(inv, (r & 3) + 8 * (r >> 2) + 4 * hi, 64);
    #pragma unroll
    for (int db = 0; db < 2; ++db)
      #pragma unroll
      for (int r = 0; r < 16; ++r) {
        const int qr = (r & 3) + 8 * (r >> 2) + 4 * hi;
        optr[(size_t)(qw + qr) * DH + db * 32 + l31] = oacc[db][r] * iw[r];
      }
  }
}

// Merge the two kv-half partials: out = (n0*e^{m0-m} + n1*e^{m1-m}) / (l0*e^{m0-m} + l1*e^{m1-m})
__global__ __launch_bounds__(256)
void attn_combine(const float* __restrict__ PO1, const float* __restrict__ PM,
                  const float* __restrict__ PL, float* __restrict__ O)
{
  const size_t idx = (size_t)blockIdx.x * 256 + threadIdx.x;  // floatx4 index
  const size_t row = idx >> 4;                                // (bh*2048 + q)
  const float m0 = PM[row], m1 = PM[NROWS + row];
  const float l0 = PL[row], l1 = PL[NROWS + row];
  const float m  = fmaxf(m0, m1);
  const float f0 = __expf(m0 - m);
  const float f1 = __expf(m1 - m);
  const float inv = 1.0f / (l0 * f0 + l1 * f1);
  floatx4 a = ((const floatx4*)O)[idx];
  floatx4 b = ((const floatx4*)PO1)[idx];
  ((floatx4*)O)[idx] = (a * f0 + b * f1) * inv;
}

extern "C" void kernel_launch(void* const* d_in, const int* in_sizes, int n_in,
                              void* d_out, int out_size, void* d_ws, size_t ws_size,
                              hipStream_t stream) {
  const float* q  = (const float*)d_in[0];
  const float* v  = (const float*)d_in[1];
  const float* k  = (const float*)d_in[2];
  const float* am = (const float*)d_in[3];
  const float* sm = (const float*)d_in[4];
  float* o = (float*)d_out;

  // ws layout: PO1 (half-1 numerator) | PM[2][NROWS] | PL[2][NROWS]
  const size_t po1_f = NROWS * DH;            // 4,194,304 floats
  const size_t ml_f  = 2 * NROWS;             // 131,072 floats each
  const size_t need  = (po1_f + 2 * ml_f) * sizeof(float);  // ~17.8 MB

  if (ws_size >= need) {
    float* po1 = (float*)d_ws;
    float* pm  = po1 + po1_f;
    float* pl  = pm + ml_f;
    dim3 grid(32, S_LEN / QBLK, 2);
    attn_fwd<true><<<grid, 256, 0, stream>>>(q, v, k, am, sm, o, po1, pm, pl);
    attn_combine<<<(NROWS * DH / 4) / 256, 256, 0, stream>>>(po1, pm, pl, o);
  } else {
    dim3 grid(32, S_LEN / QBLK, 1);
    attn_fwd<false><<<grid, 256, 0, stream>>>(q, v, k, am, sm, o,
                                              nullptr, nullptr, nullptr);
  }
}

// Round 10
// 143.431 us; speedup vs baseline: 3.2870x; 3.2870x over previous
//
#include <hip/hip_runtime.h>
#include <hip/hip_bf16.h>
#include <stdint.h>

typedef __attribute__((ext_vector_type(8)))  short    short8;
typedef __attribute__((ext_vector_type(4)))  float    floatx4;
typedef __attribute__((ext_vector_type(16))) float    floatx16;
typedef __attribute__((ext_vector_type(2)))  uint32_t uintx2;

// HW packed fp32->bf16 (RTNE), low half = first operand.
static __device__ __forceinline__ uint32_t cvtpk(float lo, float hi) {
  uint32_t r;
  asm("v_cvt_pk_bf16_f32 %0, %1, %2" : "=v"(r) : "v"(lo), "v"(hi));
  return r;
}

static __device__ __forceinline__ short8 pack8c(floatx4 a, floatx4 b) {
  union { uint32_t u[4]; short8 s; } r;
  r.u[0] = cvtpk(a[0], a[1]); r.u[1] = cvtpk(a[2], a[3]);
  r.u[2] = cvtpk(b[0], b[1]); r.u[3] = cvtpk(b[2], b[3]);
  return r.s;
}

#define MFMA32(a, b, c) __builtin_amdgcn_mfma_f32_32x32x16_bf16((a), (b), (c), 0, 0, 0)

// end-of-tile barrier: retire LDS ops, then s_barrier. Global loads stay in flight (T4).
#define TILE_BARRIER() asm volatile("s_waitcnt lgkmcnt(0)\n\ts_barrier" ::: "memory")

constexpr int S_LEN = 2048;
constexpr int DH    = 64;
constexpr int QBLK  = 128;   // 4 waves x 32 q-rows
constexpr int KVBLK = 64;
constexpr int NT    = S_LEN / KVBLK;          // 32

// permlane32_swap: new_a = [a.lo32, b.lo32] ; new_b = [a.hi32, b.hi32]
static __device__ __forceinline__ void swap32(uint32_t& a, uint32_t& b, int hi) {
#if __has_builtin(__builtin_amdgcn_permlane32_swap)
  typedef int intx2 __attribute__((ext_vector_type(2)));
  intx2 r = __builtin_amdgcn_permlane32_swap((int)a, (int)b, false, false);
  a = (uint32_t)r[0]; b = (uint32_t)r[1];
#else
  uint32_t pa = (uint32_t)__shfl_xor((int)a, 32, 64);
  uint32_t pb = (uint32_t)__shfl_xor((int)b, 32, 64);
  uint32_t na = hi ? pb : a;
  uint32_t nb = hi ? b  : pa;
  a = na; b = nb;
#endif
}

// (256,2): 256-unified-reg/wave budget. Live set ~216 with the 2-deep K/V
// pipeline -> fits WITHOUT spill. (256,3)/(256,4) proved to force spill tiers
// (r7: 64 VGPR / r9: 84 VGPR, FETCH 0.65-1.0 GB, ~500 us). 2 waves/SIMD is
// this structure's ceiling; we buy latency cover with registers instead.
__global__ __launch_bounds__(256, 2)
void attn_fwd(const float* __restrict__ Q, const float* __restrict__ V,
              const float* __restrict__ K, const float* __restrict__ AM,
              const float* __restrict__ SM, float* __restrict__ O)
{
  __shared__ ushort Kl[2][KVBLK * DH];   // [kv][d]  bf16, chunk^=(row&7) swizzle
  __shared__ ushort Vt[2][DH * KVBLK];   // [d][kv]  bf16 (plain V), swizzled

  const int bh   = blockIdx.x;
  const int qt   = blockIdx.y;

  const int tid  = threadIdx.x;
  const int lane = tid & 63;
  const int wave = tid >> 6;
  const int l31  = lane & 31;
  const int hi   = lane >> 5;

  const float* qptr  = Q  + (size_t)bh * S_LEN * DH;
  const float* kptr  = K  + (size_t)bh * S_LEN * DH;
  const float* vptr  = V  + (size_t)bh * S_LEN * DH;
  const float* amptr = AM + (size_t)(bh >> 4) * S_LEN * S_LEN;
  const float* smptr = SM + (size_t)(bh >> 4) * S_LEN;
  float* optr = O + (size_t)bh * S_LEN * DH;

  const int qw = qt * QBLK + wave * 32;  // this wave's q base

  // ---- Q fragments: lane holds Q[qw + (l&31)][s*16 + hi*8 + 0..7] ----
  short8 qf[4];
  {
    const float* p = qptr + (size_t)(qw + l31) * DH + hi * 8;
    #pragma unroll
    for (int s = 0; s < 4; ++s) {
      floatx4 f0 = *(const floatx4*)(p + s * 16);
      floatx4 f1 = *(const floatx4*)(p + s * 16 + 4);
      qf[s] = pack8c(f0, f1);
    }
  }

  // staging indices
  const int krow = tid >> 2;          // K: one kv row, 16 d
  const int kcol = (tid & 3) * 16;
  const int kcb  = (tid & 3) * 2;
  const int vr0  = (tid & 15) * 4;    // V: 4 kv rows, 4 d
  const int vd0  = (tid >> 4) * 4;

  // TWO K/V register sets: 2-tile-deep pipeline (load at t, write to LDS at t+1..2)
  floatx4 kregA[4], vregA[4], kregB[4], vregB[4];
  floatx4 amx[2][4];                  // single am buffer, 1-tile-deep (reloaded in place)

  auto LOADKV = [&](int t, floatx4 (&kreg)[4], floatx4 (&vreg)[4]) {
    const float* kg = kptr + (size_t)(t * KVBLK + krow) * DH + kcol;
    #pragma unroll
    for (int j = 0; j < 4; ++j) kreg[j] = ((const floatx4*)kg)[j];
    #pragma unroll
    for (int i = 0; i < 4; ++i)
      vreg[i] = *(const floatx4*)(vptr + (size_t)(t * KVBLK + vr0 + i) * DH + vd0);
  };

  auto WRITEKV = [&](int c, floatx4 (&kreg)[4], floatx4 (&vreg)[4]) {
    // K tile [kv][d]
    const int sw = krow & 7;
    *(short8*)&Kl[c][krow * 64 + ((kcb ^ sw) * 8)]       = pack8c(kreg[0], kreg[1]);
    *(short8*)&Kl[c][krow * 64 + (((kcb + 1) ^ sw) * 8)] = pack8c(kreg[2], kreg[3]);
    // V^T tile [d][kv] (plain bf16(V))
    #pragma unroll
    for (int d = 0; d < 4; ++d) {
      uintx2 w;
      w[0] = cvtpk(vreg[0][d], vreg[1][d]);
      w[1] = cvtpk(vreg[2][d], vreg[3][d]);
      const int row = vd0 + d;
      const int ch  = (vr0 >> 3) ^ (row & 7);
      *(uintx2*)&Vt[c][row * 64 + ch * 8 + (vr0 & 7)] = w;
    }
  };

  auto LOADAM = [&](int t) {
    const float* base = amptr + (size_t)(qw + l31) * S_LEN + t * KVBLK + hi * 4;
    #pragma unroll
    for (int blk = 0; blk < 2; ++blk)
      #pragma unroll
      for (int j = 0; j < 4; ++j)
        amx[blk][j] = *(const floatx4*)(base + blk * 32 + j * 8);
  };

  // prologue: tile0 -> LDS (via set A), tile1 -> set B (stays in regs), am(0)
  LOADKV(0, kregA, vregA);
  WRITEKV(0, kregA, vregA);
  LOADKV(1, kregB, vregB);
  LOADAM(0);
  TILE_BARRIER();

  float m_run = -3.0e38f, l_run = 0.f;
  floatx16 oacc[2];
  #pragma unroll
  for (int db = 0; db < 2; ++db)
    #pragma unroll
    for (int r = 0; r < 16; ++r) oacc[db][r] = 0.f;

  // one K/V-tile step. c = LDS buffer holding tile tt.
  // kW/vW hold tile tt+1 (written to LDS now); kL/vL receive tile tt+2.
  auto STEP = [&](int tt, int c,
                  floatx4 (&kW)[4], floatx4 (&vW)[4],
                  floatx4 (&kL)[4], floatx4 (&vL)[4]) {
    // ---- QK^T: sc[blk] = S^T[kv][q]; lane q=l31, kv = blk*32+crow(r,hi) ----
    floatx16 sc[2];   // MFMA acc -> scores -> P, in place
    __builtin_amdgcn_s_setprio(1);
    #pragma unroll
    for (int blk = 0; blk < 2; ++blk) {
      #pragma unroll
      for (int r = 0; r < 16; ++r) sc[blk][r] = 0.f;
      const int row = blk * 32 + l31;
      const int sw  = row & 7;
      #pragma unroll
      for (int s = 0; s < 4; ++s) {
        const int ch = (s * 2 + hi) ^ sw;
        short8 kf = *(const short8*)&Kl[c][row * 64 + ch * 8];
        sc[blk] = MFMA32(kf, qf[s], sc[blk]);
      }
    }
    __builtin_amdgcn_s_setprio(0);

    // ---- scores in place (consumes amx loaded one tile ago) ----
    float pmax = -3.0e38f;
    #pragma unroll
    for (int blk = 0; blk < 2; ++blk)
      #pragma unroll
      for (int r = 0; r < 16; ++r) {
        const float v = fmaf(sc[blk][r], 0.125f, amx[blk][r >> 2][r & 3]);
        sc[blk][r] = v;
        pmax = fmaxf(pmax, v);
      }
    pmax = fmaxf(pmax, __shfl_xor(pmax, 32, 64));

    // ---- am regs dead: reload in place for next tile (1-tile cover) ----
    const int tn = (tt + 1 < NT) ? tt + 1 : NT - 1;
    LOADAM(tn);

    // ---- seq_mask fragments (global, L1-resident broadcast) ----
    floatx4 smv[2][4];
    #pragma unroll
    for (int blk = 0; blk < 2; ++blk)
      #pragma unroll
      for (int j = 0; j < 4; ++j)
        smv[blk][j] = *(const floatx4*)(smptr + tt * KVBLK + blk * 32 + hi * 4 + j * 8);

    // ---- online rescale (skip is bit-exact when no row grew: fac==1.0) ----
    if (__any(pmax > m_run)) {
      const float mnew = fmaxf(m_run, pmax);
      const float fac  = __expf(m_run - mnew);
      float fw[16];
      #pragma unroll
      for (int r = 0; r < 16; ++r)
        fw[r] = __shfl(fac, (r & 3) + 8 * (r >> 2) + 4 * hi, 64);
      #pragma unroll
      for (int db = 0; db < 2; ++db)
        #pragma unroll
        for (int r = 0; r < 16; ++r) oacc[db][r] *= fw[r];
      l_run *= fac;
      m_run = mnew;
    }

    // ---- P = exp(s - m) in place; denominator from UNROUNDED fp32 P ----
    float ssum = 0.f;
    #pragma unroll
    for (int blk = 0; blk < 2; ++blk)
      #pragma unroll
      for (int r = 0; r < 16; ++r) {
        const float e = __expf(sc[blk][r] - m_run);
        sc[blk][r] = e;
        ssum += e;
      }
    ssum += __shfl_xor(ssum, 32, 64);
    l_run += ssum;

    // ---- (P * sm) -> bf16 A-fragments (cvt_pk + permlane32_swap) ----
    uint32_t pw[2][2][4];
    #pragma unroll
    for (int blk = 0; blk < 2; ++blk)
      #pragma unroll
      for (int ks = 0; ks < 2; ++ks) {
        uint32_t w0 = cvtpk(sc[blk][ks * 8 + 0] * smv[blk][ks * 2 + 0][0],
                            sc[blk][ks * 8 + 1] * smv[blk][ks * 2 + 0][1]);
        uint32_t w1 = cvtpk(sc[blk][ks * 8 + 2] * smv[blk][ks * 2 + 0][2],
                            sc[blk][ks * 8 + 3] * smv[blk][ks * 2 + 0][3]);
        uint32_t w2 = cvtpk(sc[blk][ks * 8 + 4] * smv[blk][ks * 2 + 1][0],
                            sc[blk][ks * 8 + 5] * smv[blk][ks * 2 + 1][1]);
        uint32_t w3 = cvtpk(sc[blk][ks * 8 + 6] * smv[blk][ks * 2 + 1][2],
                            sc[blk][ks * 8 + 7] * smv[blk][ks * 2 + 1][3]);
        swap32(w0, w2, hi);
        swap32(w1, w3, hi);
        pw[blk][ks][0] = w0; pw[blk][ks][1] = w1;
        pw[blk][ks][2] = w2; pw[blk][ks][3] = w3;
      }

    // ---- PV: oacc[db] += (P.sm)(32q x 64kv) . V(64kv x 64d) ----
    __builtin_amdgcn_s_setprio(1);
    #pragma unroll
    for (int blk = 0; blk < 2; ++blk)
      #pragma unroll
      for (int ks = 0; ks < 2; ++ks) {
        union { uint32_t u[4]; short8 s; } af;
        af.u[0] = pw[blk][ks][0]; af.u[1] = pw[blk][ks][1];
        af.u[2] = pw[blk][ks][2]; af.u[3] = pw[blk][ks][3];
        #pragma unroll
        for (int db = 0; db < 2; ++db) {
          const int row = db * 32 + l31;
          const int ch  = (blk * 4 + ks * 2 + hi) ^ (row & 7);
          short8 vf = *(const short8*)&Vt[c][row * 64 + ch * 8];
          oacc[db] = MFMA32(af.s, vf, oacc[db]);
        }
      }
    __builtin_amdgcn_s_setprio(0);

    // ---- LDS <- tile tt+1 (regs loaded 1.5-2 tiles ago: deep vmcnt cover) ----
    WRITEKV(c ^ 1, kW, vW);
    // ---- issue tile tt+2 loads into the now-free set ----
    const int t2 = (tt + 2 < NT) ? tt + 2 : NT - 1;
    LOADKV(t2, kL, vL);
    TILE_BARRIER();
  };

  #pragma unroll 1
  for (int t = 0; t < NT; t += 2) {
    STEP(t,     0, kregB, vregB, kregA, vregA);
    STEP(t + 1, 1, kregA, vregA, kregB, vregB);
  }

  // ---- epilogue: out = oacc / l ----
  const float inv = 1.0f / l_run;
  float iw[16];
  #pragma unroll
  for (int r = 0; r < 16; ++r)
    iw[r] = __shfl(inv, (r & 3) + 8 * (r >> 2) + 4 * hi, 64);
  #pragma unroll
  for (int db = 0; db < 2; ++db)
    #pragma unroll
    for (int r = 0; r < 16; ++r) {
      const int qr = (r & 3) + 8 * (r >> 2) + 4 * hi;
      optr[(size_t)(qw + qr) * DH + db * 32 + l31] = oacc[db][r] * iw[r];
    }
}

extern "C" void kernel_launch(void* const* d_in, const int* in_sizes, int n_in,
                              void* d_out, int out_size, void* d_ws, size_t ws_size,
                              hipStream_t stream) {
  const float* q  = (const float*)d_in[0];
  const float* v  = (const float*)d_in[1];
  const float* k  = (const float*)d_in[2];
  const float* am = (const float*)d_in[3];
  const float* sm = (const float*)d_in[4];
  float* o = (float*)d_out;

  dim3 grid(32, S_LEN / QBLK);  // (b*h, q-tile of 128)
  attn_fwd<<<grid, 256, 0, stream>>>(q, v, k, am, sm, o);
}